// Round 3
// baseline (229.987 us; speedup 1.0000x reference)
//
#include <hip/hip_runtime.h>

#define HWPIX 16384
#define XSTR 200   // lx stride in shorts (100 words); per-wave quarter also hosts lh
#define HSTR 104   // lh stride in shorts (52 words)
#define L2E 1.4426950408889634f

typedef float f32x4 __attribute__((ext_vector_type(4)));
typedef short s16x8 __attribute__((ext_vector_type(8)));

static __device__ __forceinline__ unsigned short f2bf(float f) {
    unsigned int u = __builtin_bit_cast(unsigned int, f);
    u += 0x7fffu + ((u >> 16) & 1u);
    return (unsigned short)(u >> 16);
}
static __device__ __forceinline__ unsigned int pack2(float lo, float hi) {
    return (unsigned int)f2bf(lo) | ((unsigned int)f2bf(hi) << 16);
}
// HW packed f32->bf16 (RNE), one instruction for two converts
static __device__ __forceinline__ unsigned int cvtpk(float lo, float hi) {
    unsigned int r;
    asm("v_cvt_pk_bf16_f32 %0, %1, %2" : "=v"(r) : "v"(lo), "v"(hi));
    return r;
}

// ws layout: floats [0,1536) gmean, [1536,3072) xg, [3072,3168) s1l, [3168,3264) t1l,
// [3264,3456) s2l, [3456,3648) t2l. Byte 16384: W1 bf16 frags (36864 B), then W2 frags.

__global__ __launch_bounds__(256) void prep_kernel(
    const float* __restrict__ x1, const float* __restrict__ x2, const float* __restrict__ x3,
    const float* __restrict__ lw1, const float* __restrict__ lb1,
    const float* __restrict__ lg1, const float* __restrict__ lbe1,
    const float* __restrict__ lm1, const float* __restrict__ lv1,
    const float* __restrict__ lw2, const float* __restrict__ lb2,
    const float* __restrict__ lg2, const float* __restrict__ lbe2,
    const float* __restrict__ lm2, const float* __restrict__ lv2,
    float* __restrict__ wsf, unsigned short* __restrict__ w1f, unsigned short* __restrict__ w2f)
{
    const int bid = blockIdx.x, t = threadIdx.x;
    if (bid < 1536) {
        // GAP over one (b, channel) fp32 plane: 16384 floats
        int b = bid / 192, c = bid % 192;
        int g = c >> 6, cc = c & 63;
        const float* base = (g == 0 ? x1 : (g == 1 ? x2 : x3)) + ((size_t)(b * 64 + cc)) * HWPIX;
        float s = 0.f;
        #pragma unroll
        for (int it = 0; it < 16; ++it) {
            f32x4 v = *(const f32x4*)(base + it * 1024 + t * 4);
            s += v[0] + v[1] + v[2] + v[3];
        }
        for (int off = 32; off > 0; off >>= 1) s += __shfl_down(s, off, 64);
        __shared__ float part[4];
        if ((t & 63) == 0) part[t >> 6] = s;
        __syncthreads();
        if (t == 0) wsf[bid] = (part[0] + part[1] + part[2] + part[3]) * (1.f / (float)HWPIX);
    } else if (bid == 1536) {
        if (t < 96) {
            float s = lg1[t] * __frsqrt_rn(lv1[t] + 1e-5f);
            wsf[3072 + t] = s;
            wsf[3168 + t] = (lb1[t] - lm1[t]) * s + lbe1[t];
        }
    } else if (bid == 1537) {
        if (t < 192) {
            float s = lg2[t] * __frsqrt_rn(lv2[t] + 1e-5f);
            wsf[3264 + t] = s;
            wsf[3456 + t] = (lb2[t] - lm2[t]) * s + lbe2[t];
        }
    } else if (bid < 1547) {
        // W1 pretile fp32 -> bf16 B-frags. frag f = kb*6+nb; lane l holds
        // B[k=(l>>4)*8+j][n=l&15] with B=W1^T -> W1[row=n][col=k..k+7]
        int slot = (bid - 1538) * 256 + t;          // [0, 2304)
        int f = slot >> 6, l = slot & 63;
        int kb = f / 6, nb = f % 6;
        int row = nb * 16 + (l & 15), col0 = kb * 32 + ((l >> 4) << 3);
        const float* src = lw1 + row * 192 + col0;
        f32x4 a = *(const f32x4*)src, b4 = *(const f32x4*)(src + 4);
        unsigned int* dst = (unsigned int*)(w1f + f * 512 + l * 8);
        dst[0] = pack2(a[0], a[1]); dst[1] = pack2(a[2], a[3]);
        dst[2] = pack2(b4[0], b4[1]); dst[3] = pack2(b4[2], b4[3]);
    } else {
        // W2 pretile: frag f = kb*12+nb; W2[row=n][col=k..k+7], rows 0..191, cols 0..95
        int slot = (bid - 1547) * 256 + t;
        int f = slot >> 6, l = slot & 63;
        int kb = f / 12, nb = f % 12;
        int row = nb * 16 + (l & 15), col0 = kb * 32 + ((l >> 4) << 3);
        const float* src = lw2 + row * 96 + col0;
        f32x4 a = *(const f32x4*)src, b4 = *(const f32x4*)(src + 4);
        unsigned int* dst = (unsigned int*)(w2f + f * 512 + l * 8);
        dst[0] = pack2(a[0], a[1]); dst[1] = pack2(a[2], a[3]);
        dst[2] = pack2(b4[0], b4[1]); dst[3] = pack2(b4[2], b4[3]);
    }
}

__global__ __launch_bounds__(256) void gpath_kernel(
    const float* __restrict__ gw1, const float* __restrict__ gb1,
    const float* __restrict__ gg1, const float* __restrict__ gbe1,
    const float* __restrict__ gm1, const float* __restrict__ gv1,
    const float* __restrict__ gw2, const float* __restrict__ gb2,
    const float* __restrict__ gg2, const float* __restrict__ gbe2,
    const float* __restrict__ gm2, const float* __restrict__ gv2,
    float* __restrict__ wsf)
{
    __shared__ float xbar[192], hbuf[96];
    const int b = blockIdx.x, t = threadIdx.x;
    if (t < 192) xbar[t] = wsf[b * 192 + t];
    __syncthreads();
    if (t < 96) {
        float acc = 0.f;
        #pragma unroll 8
        for (int c = 0; c < 192; ++c) acc += gw1[t * 192 + c] * xbar[c];
        float s = gg1[t] * __frsqrt_rn(gv1[t] + 1e-5f);
        float tt = (gb1[t] - gm1[t]) * s + gbe1[t];
        hbuf[t] = fmaxf(acc * s + tt, 0.f);
    }
    __syncthreads();
    if (t < 192) {
        float acc = 0.f;
        #pragma unroll 8
        for (int j = 0; j < 96; ++j) acc += gw2[t * 96 + j] * hbuf[j];
        float s = gg2[t] * __frsqrt_rn(gv2[t] + 1e-5f);
        float tt = (gb2[t] - gm2[t]) * s + gbe2[t];
        wsf[1536 + b * 192 + t] = acc * s + tt;
    }
}

// 64-pixel tiles, 2048 blocks. LDS = 25600 (lx, hosts lh per-wave) + 2304 (lpar)
// = 27904 B. ONE barrier. All memory phases are batched (issue-all-then-use) and
// the weight frags are register-double-buffered to keep many loads in flight.
__global__ __launch_bounds__(256, 4) void main_kernel(
    const float* __restrict__ x1, const float* __restrict__ x2, const float* __restrict__ x3,
    const float* __restrict__ wsf,
    const unsigned short* __restrict__ w1f, const unsigned short* __restrict__ w2f,
    float* __restrict__ out)
{
    __shared__ __align__(16) unsigned short lx[64 * XSTR];   // bf16 [pix][ch]; lh aliases
    __shared__ float lpar[576];   // s1[96] t1[96] | A2[192] B2[192] (pre-scaled epilogue)

    const int t = threadIdx.x;
    const int b = blockIdx.x >> 8;
    const int pix0 = (blockIdx.x & 255) << 6;
    const int lane = t & 63;
    const int wv = t >> 6;
    const int col = lane & 15;
    const int q = lane >> 4;
    const int pixw = wv * 16;

    const unsigned short* wb1 = w1f + lane * 8;
    const unsigned short* wb2 = w2f + lane * 8;

    // ---- X staging, batched: issue ALL 12 HBM loads, then convert+write ----
    f32x4 va[6], vb[6];
    {
        const int pq = t >> 4;        // pixel quad 0..15
        const int cb = t & 15;
        #pragma unroll
        for (int i = 0; i < 6; ++i) {
            int cp = i * 16 + cb;     // channel pair 0..95
            int c0 = cp * 2;
            int g = c0 >> 6, cc0 = c0 & 63;
            const float* pl = (g == 0 ? x1 : (g == 1 ? x2 : x3))
                + ((size_t)(b * 64 + cc0)) * HWPIX + pix0 + pq * 4;
            va[i] = *(const f32x4*)pl;
            vb[i] = *(const f32x4*)(pl + HWPIX);   // channel c0+1, same group
        }
    }

    // W1 kb0 frags: issue before the barrier (independent of LDS)
    s16x8 wcur[6];
    #pragma unroll
    for (int nb = 0; nb < 6; ++nb) wcur[nb] = *(const s16x8*)(wb1 + nb * 512);

    if (t < 96)  { lpar[t] = wsf[3072 + t]; lpar[96 + t] = wsf[3168 + t]; }
    if (t < 192) {
        // sigmoid(acc*s2 + t2 + xg) = rcp(1 + exp2(acc*A + B))
        float s2 = wsf[3264 + t], t2 = wsf[3456 + t], xg = wsf[1536 + b * 192 + t];
        lpar[192 + t] = -L2E * s2;
        lpar[384 + t] = -L2E * (t2 + xg);
    }
    {
        const int pq = t >> 4;
        const int cb = t & 15;
        unsigned int* lx32 = (unsigned int*)lx;
        #pragma unroll
        for (int i = 0; i < 6; ++i) {
            int cp = i * 16 + cb;
            #pragma unroll
            for (int j = 0; j < 4; ++j)
                lx32[(pq * 4 + j) * 100 + cp] = cvtpk(va[i][j], vb[i][j]);
        }
    }
    __syncthreads();   // the ONLY barrier: lx + lpar published

    unsigned short* lhp = &lx[pixw * XSTR];  // per-wave lh region (private to this wave)

    // ---- Phase 1: H = relu(bn1(X @ W1^T)), K=192; reg-dbuf weight pipeline ----
    s16x8 a1[6];
    #pragma unroll
    for (int kb = 0; kb < 6; ++kb)
        a1[kb] = *(const s16x8*)&lx[(pixw + col) * XSTR + kb * 32 + q * 8];

    f32x4 acc1[6];
    #pragma unroll
    for (int nb = 0; nb < 6; ++nb) acc1[nb] = (f32x4){0.f, 0.f, 0.f, 0.f};

    s16x8 wnxt[6];
    #pragma unroll
    for (int kb = 0; kb < 6; ++kb) {
        if (kb < 5) {
            #pragma unroll
            for (int nb = 0; nb < 6; ++nb)
                wnxt[nb] = *(const s16x8*)(wb1 + ((kb + 1) * 6 + nb) * 512);
        }
        #pragma unroll
        for (int nb = 0; nb < 6; ++nb)
            acc1[nb] = __builtin_amdgcn_mfma_f32_16x16x32_bf16(a1[kb], wcur[nb], acc1[nb], 0, 0, 0);
        if (kb < 5) {
            #pragma unroll
            for (int nb = 0; nb < 6; ++nb) wcur[nb] = wnxt[nb];
        }
    }

    // W2 step-0 frags (h=0): issue now; latency covered by the lh writes below
    s16x8 v2cur[6];
    #pragma unroll
    for (int i = 0; i < 6; ++i) v2cur[i] = *(const s16x8*)(wb2 + i * 512);

    // lh write into own lx quarter (wave-private; per-wave DS ordering suffices)
    #pragma unroll
    for (int nbp = 0; nbp < 3; ++nbp) {
        int j0 = (2 * nbp) * 16 + col, j1 = (2 * nbp + 1) * 16 + col;
        float s0 = lpar[j0], t0 = lpar[96 + j0];
        float s1v = lpar[j1], t1v = lpar[96 + j1];
        #pragma unroll
        for (int r = 0; r < 4; ++r) {
            float h0 = fmaxf(acc1[2 * nbp][r] * s0 + t0, 0.f);
            float h1 = fmaxf(acc1[2 * nbp + 1][r] * s1v + t1v, 0.f);
            unsigned int w = cvtpk(h0, h1);
            int rowo = (q * 4 + r) * HSTR;
            lhp[rowo + j0] = (unsigned short)w;
            lhp[rowo + j1] = (unsigned short)(w >> 16);
        }
    }

    // ---- Phase 2: XL = bn2(H @ W2^T), K=96; 6 half-steps of 6 MFMAs, reg-dbuf ----
    s16x8 a2[3];
    #pragma unroll
    for (int kb = 0; kb < 3; ++kb)
        a2[kb] = *(const s16x8*)&lhp[col * HSTR + kb * 32 + q * 8];

    f32x4 acc2[12];
    #pragma unroll
    for (int nb = 0; nb < 12; ++nb) acc2[nb] = (f32x4){0.f, 0.f, 0.f, 0.f};

    s16x8 v2nxt[6];
    #pragma unroll
    for (int h = 0; h < 6; ++h) {            // frag set h = frags h*6 .. h*6+5
        int kb = h >> 1, nbo = (h & 1) * 6;
        if (h < 5) {
            #pragma unroll
            for (int i = 0; i < 6; ++i)
                v2nxt[i] = *(const s16x8*)(wb2 + ((h + 1) * 6 + i) * 512);
        }
        #pragma unroll
        for (int i = 0; i < 6; ++i)
            acc2[nbo + i] = __builtin_amdgcn_mfma_f32_16x16x32_bf16(a2[kb], v2cur[i], acc2[nbo + i], 0, 0, 0);
        if (h < 5) {
            #pragma unroll
            for (int i = 0; i < 6; ++i) v2cur[i] = v2nxt[i];
        }
    }

    // ---- Epilogue: batch all 12 x re-reads (L2 hits), then compute ----
    f32x4 xa[4], xb4[4], xc4[4];
    size_t po[4];
    #pragma unroll
    for (int nb = 0; nb < 4; ++nb) {
        int cc = nb * 16 + col;
        po[nb] = ((size_t)(b * 64 + cc)) * HWPIX + pix0 + pixw + q * 4;
        xa[nb]  = *(const f32x4*)(x1 + po[nb]);
        xb4[nb] = *(const f32x4*)(x2 + po[nb]);
        xc4[nb] = *(const f32x4*)(x3 + po[nb]);
    }
    #pragma unroll
    for (int nb = 0; nb < 4; ++nb) {
        int cc = nb * 16 + col;   // output channel; triplet at nb, nb+4, nb+8
        float A0 = lpar[192 + cc],       B0 = lpar[384 + cc];
        float A1 = lpar[192 + 64 + cc],  B1 = lpar[384 + 64 + cc];
        float A2 = lpar[192 + 128 + cc], B2 = lpar[384 + 128 + cc];
        f32x4 res;
        #pragma unroll
        for (int r = 0; r < 4; ++r) {
            // wi = sigmoid(vi) in (0,1)  ->  exp(wi) in (1,e): no max-sub needed
            float w0 = __builtin_amdgcn_rcpf(1.f + __builtin_amdgcn_exp2f(acc2[nb][r]     * A0 + B0));
            float w1 = __builtin_amdgcn_rcpf(1.f + __builtin_amdgcn_exp2f(acc2[nb + 4][r] * A1 + B1));
            float w2 = __builtin_amdgcn_rcpf(1.f + __builtin_amdgcn_exp2f(acc2[nb + 8][r] * A2 + B2));
            float e0 = __builtin_amdgcn_exp2f(w0 * L2E);
            float e1 = __builtin_amdgcn_exp2f(w1 * L2E);
            float e2 = __builtin_amdgcn_exp2f(w2 * L2E);
            float inv = __builtin_amdgcn_rcpf(e0 + e1 + e2);
            res[r] = (e0 * xa[nb][r] + e1 * xb4[nb][r] + e2 * xc4[nb][r]) * inv;
        }
        *(f32x4*)(out + po[nb]) = res;
    }
}

extern "C" void kernel_launch(void* const* d_in, const int* in_sizes, int n_in,
                              void* d_out, int out_size, void* d_ws, size_t ws_size,
                              hipStream_t stream) {
    (void)in_sizes; (void)n_in; (void)out_size; (void)ws_size;
    const float* x1  = (const float*)d_in[0];
    const float* x2  = (const float*)d_in[1];
    const float* x3  = (const float*)d_in[2];
    const float* lw1 = (const float*)d_in[3];
    const float* lb1 = (const float*)d_in[4];
    const float* lg1 = (const float*)d_in[5];
    const float* lbe1= (const float*)d_in[6];
    const float* lm1 = (const float*)d_in[7];
    const float* lv1 = (const float*)d_in[8];
    const float* lw2 = (const float*)d_in[9];
    const float* lb2 = (const float*)d_in[10];
    const float* lg2 = (const float*)d_in[11];
    const float* lbe2= (const float*)d_in[12];
    const float* lm2 = (const float*)d_in[13];
    const float* lv2 = (const float*)d_in[14];
    const float* gw1 = (const float*)d_in[15];
    const float* gb1 = (const float*)d_in[16];
    const float* gg1 = (const float*)d_in[17];
    const float* gbe1= (const float*)d_in[18];
    const float* gm1 = (const float*)d_in[19];
    const float* gv1 = (const float*)d_in[20];
    const float* gw2 = (const float*)d_in[21];
    const float* gb2 = (const float*)d_in[22];
    const float* gg2 = (const float*)d_in[23];
    const float* gbe2= (const float*)d_in[24];
    const float* gm2 = (const float*)d_in[25];
    const float* gv2 = (const float*)d_in[26];

    float* wsf = (float*)d_ws;
    unsigned short* w1f = (unsigned short*)((char*)d_ws + 16384);
    unsigned short* w2f = w1f + 18432;   // 36864 bytes after w1f

    prep_kernel<<<1556, 256, 0, stream>>>(x1, x2, x3,
        lw1, lb1, lg1, lbe1, lm1, lv1, lw2, lb2, lg2, lbe2, lm2, lv2,
        wsf, w1f, w2f);
    gpath_kernel<<<8, 256, 0, stream>>>(
        gw1, gb1, gg1, gbe1, gm1, gv1, gw2, gb2, gg2, gbe2, gm2, gv2, wsf);
    main_kernel<<<2048, 256, 0, stream>>>(x1, x2, x3, wsf, w1f, w2f, (float*)d_out);
}